// Round 1
// baseline (336.433 us; speedup 1.0000x reference)
//
#include <hip/hip_runtime.h>
#include <math.h>

// Problem constants
constexpr int BQ = 32;       // query batch
constexpr int C  = 256;      // channels
constexpr int HW = 4096;     // 64*64
constexpr int W  = 64;
constexpr int P  = 256;      // protos (4 * 8 * 8)
constexpr float THRESH = 0.95f;
constexpr float SCALE  = 20.0f;
constexpr float EPSF   = 1e-4f;
constexpr double EPSD  = 1e-4;
constexpr float GAP_THRESH = 2e-3f;   // split-bf16 dist err ~5e-4 -> 4x margin
constexpr int MAXSUS = 65536;

// d_out layout: pred [0, 131072) | debug_assign [131072, 262144) | proto_grid [262144, 278528)
constexpr int OUT_ASSIGN = BQ * HW;
constexpr int OUT_GRID   = 2 * BQ * HW;

typedef __attribute__((ext_vector_type(8))) short short8;
typedef __attribute__((ext_vector_type(4))) float floatx4;

static __device__ __forceinline__ unsigned short f2bf(float x) {
    unsigned u = __float_as_uint(x);
    u += 0x7FFFu + ((u >> 16) & 1u);     // round-to-nearest-even (no NaN inputs)
    return (unsigned short)(u >> 16);
}
static __device__ __forceinline__ float bf2f(unsigned short h) {
    return __uint_as_float(((unsigned)h) << 16);
}

// Fragment-order offset (ushort units): [tile][ks][h][lane][j], lane = quad*16 + idx,
// element j of lane <-> k = ks*32 + quad*8 + j. A and B use the IDENTICAL map, so
// any k-permutation cancels in the MFMA contraction.
#define FRAGOFF(tile, ks, h, lane) (((((tile) * 8 + (ks)) * 2 + (h)) * 64 + (lane)) * 8)

// async global->LDS, 16 B/lane; LDS dest = wave-uniform base + lane*16
static __device__ __forceinline__ void gl_lds16(const unsigned short* gp, unsigned short* lp) {
    __builtin_amdgcn_global_load_lds(
        (const __attribute__((address_space(1))) unsigned int*)gp,
        (__attribute__((address_space(3))) unsigned int*)lp, 16, 0, 0);
}

// ---------------------------------------------------------------------------
// Prep: pooled protos (fp64 normalize) -> split-bf16 frag-order pB + fp64 pn64,
// valid flags, proto_grid output, zero suspect counter. Block=proto, thread=channel.
// ---------------------------------------------------------------------------
__global__ __launch_bounds__(256)
void prep_kernel(const float* __restrict__ sup_x, const float* __restrict__ sup_y,
                 float* __restrict__ out, unsigned short* __restrict__ pB,
                 double* __restrict__ pn64, int* __restrict__ valid,
                 int* __restrict__ counter)
{
    const int p = blockIdx.x;     // proto index = s*64 + gy*8 + gx
    const int t = threadIdx.x;    // channel
    const int s = p >> 6, gy = (p >> 3) & 7, gx = p & 7;

    const float* base = sup_x + ((size_t)(s * C + t)) * HW + (gy * 8) * W + gx * 8;
    double sum = 0.0;
#pragma unroll
    for (int r = 0; r < 8; ++r) {
        const float4 a  = *(const float4*)(base + r * W);
        const float4 bq = *(const float4*)(base + r * W + 4);
        sum += (double)a.x;  sum += (double)a.y;  sum += (double)a.z;  sum += (double)a.w;
        sum += (double)bq.x; sum += (double)bq.y; sum += (double)bq.z; sum += (double)bq.w;
    }
    const double mean = sum * (1.0 / 64.0);

    __shared__ double red[256];
    red[t] = mean * mean;
    __syncthreads();
    for (int off = 128; off > 0; off >>= 1) {
        if (t < off) red[t] += red[t + off];
        __syncthreads();
    }
    const double nrm = sqrt(red[0]);
    const double pnv = mean / fmax(nrm, EPSD);
    pn64[(size_t)p * C + t] = pnv;

    // split-bf16 frag-order store: nt=p>>4, n-idx=p&15; ks=c>>5, quad=(c>>3)&3, j=c&7
    const float pnf = (float)pnv;
    const unsigned short phi = f2bf(pnf);
    const unsigned short plo = f2bf(pnf - bf2f(phi));
    const int nt = p >> 4, ks = t >> 5, lane = (((t >> 3) & 3) << 4) | (p & 15), j = t & 7;
    pB[FRAGOFF(nt, ks, 0, lane) + j] = phi;
    pB[FRAGOFF(nt, ks, 1, lane) + j] = plo;

    bool mybit = false;
    if (t < 64) {
        const int r = t >> 3, k = t & 7;
        mybit = sup_y[s * HW + (gy * 8 + r) * W + gx * 8 + k] > THRESH;
    }
    const unsigned long long bm = __ballot(mybit);   // wave 0 carries t=0..63
    if (t == 0) {
        valid[p] = (__popcll(bm) > 32) ? 1 : 0;      // mask_pooled > 0.5
        if (p == 0) *counter = 0;
    }
    if (t < 64) {
        const int i = p * 64 + t;
        out[OUT_GRID + i] = (sup_y[i] > THRESH) ? 1.0f : 0.0f;
    }
}

// ---------------------------------------------------------------------------
// Main: split-bf16 MFMA dists + fused softmax/argmax/pred.
// Block = 64 positions (4 waves); wave w owns pos-tile w (16 pos) x ALL 256 protos.
// A-frags (own q, hi+lo, full K) live in REGISTERS for the whole k-loop (64 VGPRs).
//
// R1 change: DOUBLE-BUFFERED B staging (2 x 32 KiB LDS). Old structure exposed the
// full global->LDS latency per ks chunk between two barriers:
//   barrier ; stage(ks) ; barrier(vmcnt drain, block idle) ; compute(ks)
// New structure (T3 minimum 2-phase): stage(ks+1) is issued BEFORE compute(ks), and
// the single trailing __syncthreads() (implicit s_waitcnt vmcnt(0) lgkmcnt(0)) lands
// AFTER ~700 cyc of ds_read+MFMA has covered the load latency. One barrier per ks
// instead of two; no exposed drain. Hazards: barrier at end of iter ks drains this
// wave's stage-for-(ks+1) and its ds_reads of buf[ks&1]; overwrite of buf[(ks+1)&1]
// in iter ks+1 is ordered after all reads of it (iter ks-1) by the same barrier chain.
//
// launch_bounds(256,2): 256-reg/wave budget -> acc(64,AGPR)+ah/al(64)+temps fit
// WITHOUT spilling. (R5's (256,3) capped arch-VGPRs at 84 -> 64 regs/thread
// spilled to scratch -> 128 MB WRITE_SIZE, 267 MB HBM traffic, 203 us.)
// ---------------------------------------------------------------------------
__global__ __launch_bounds__(256, 2)
void dist_kernel(const float* __restrict__ qry, const unsigned short* __restrict__ pB,
                 const int* __restrict__ valid, float* __restrict__ out,
                 int* __restrict__ counter, int* __restrict__ suspects)
{
    __shared__ unsigned short ldsB[2][16 * 2 * 64 * 8];   // 2 x 32 KiB: [buf][nt][h][lane][j]
    __shared__ float scale_lds[64];
    __shared__ int   validLds[P];

    const int t    = threadIdx.x;
    const int w    = t >> 6;      // wave -> pos-tile
    const int l    = t & 63;
    const int quad = l >> 4;
    const int m    = l & 15;

    const int b    = blockIdx.x >> 6;
    const int pos0 = (blockIdx.x & 63) * 64;

    validLds[t] = valid[t];

    // ---- A staging: own pos-tile, full K, into registers (no barrier needed) ----
    // lane l covers pos = pos0 + w*16 + m, k = ks*32 + quad*8 + j
    short8 ah[8], al[8];
    float ssq = 0.f;
    {
        const float* qp = qry + (size_t)b * C * HW + pos0 + w * 16 + m;
#pragma unroll
        for (int ks = 0; ks < 8; ++ks) {
            float v[8];
#pragma unroll
            for (int j = 0; j < 8; ++j)
                v[j] = qp[(size_t)(ks * 32 + quad * 8 + j) * HW];
            short8 h8, l8;
#pragma unroll
            for (int j = 0; j < 8; ++j) {
                ssq = fmaf(v[j], v[j], ssq);
                const unsigned short hi = f2bf(v[j]);
                h8[j] = (short)hi;
                l8[j] = (short)f2bf(v[j] - bf2f(hi));
            }
            ah[ks] = h8; al[ks] = l8;
        }
    }
    // ||q||^2 for pos w*16+m: sum the 4 quads (lanes differing in bits 4,5)
    ssq += __shfl_xor(ssq, 16);
    ssq += __shfl_xor(ssq, 32);
    if (l < 16) scale_lds[w * 16 + l] = SCALE / fmaxf(sqrtf(ssq), EPSF);

    // ---- k-loop: double-buffered async B staging, 48 MFMA per ks ----
    floatx4 acc[16];
#pragma unroll
    for (int nt = 0; nt < 16; ++nt) acc[nt] = (floatx4){0.f, 0.f, 0.f, 0.f};

    // prologue: stage ks=0 into buf 0 (32 chunks of 1 KiB; wave w stages w*8..w*8+7)
#pragma unroll
    for (int i = 0; i < 8; ++i) {
        const int idx = w * 8 + i, nt = idx >> 1, h = idx & 1;
        gl_lds16(pB + FRAGOFF(nt, 0, h, 0) + l * 8,
                 &ldsB[0][(nt * 2 + h) * 512]);
    }
    __syncthreads();   // vmcnt drained -> buf0 visible; also covers scale/valid LDS writes

#pragma unroll
    for (int ks = 0; ks < 8; ++ks) {
        // issue next chunk's stage FIRST (latency hides under this chunk's compute)
        if (ks < 7) {
#pragma unroll
            for (int i = 0; i < 8; ++i) {
                const int idx = w * 8 + i, nt = idx >> 1, h = idx & 1;
                gl_lds16(pB + FRAGOFF(nt, ks + 1, h, 0) + l * 8,
                         &ldsB[(ks + 1) & 1][(nt * 2 + h) * 512]);
            }
        }
        const unsigned short* Bb = ldsB[ks & 1];
#pragma unroll
        for (int nt = 0; nt < 16; ++nt) {
            const short8 bh = *(const short8*)&Bb[((nt * 2 + 0) * 64 + l) * 8];
            const short8 bl = *(const short8*)&Bb[((nt * 2 + 1) * 64 + l) * 8];
            acc[nt] = __builtin_amdgcn_mfma_f32_16x16x32_bf16(ah[ks], bh, acc[nt], 0, 0, 0);
            acc[nt] = __builtin_amdgcn_mfma_f32_16x16x32_bf16(ah[ks], bl, acc[nt], 0, 0, 0);
            acc[nt] = __builtin_amdgcn_mfma_f32_16x16x32_bf16(al[ks], bh, acc[nt], 0, 0, 0);
        }
        if (ks < 7) __syncthreads();   // drains own stage (vmcnt) + own ds_reads (lgkm)
    }

    // ---- epilogue (wave-local). C/D: proto = nt*16 + m, pos-in-tile = quad*4 + r ----
    int vbits = 0;
#pragma unroll
    for (int nt = 0; nt < 16; ++nt) vbits |= validLds[nt * 16 + m] << nt;

    float scr[4];
#pragma unroll
    for (int r = 0; r < 4; ++r) scr[r] = scale_lds[w * 16 + quad * 4 + r];
#pragma unroll
    for (int nt = 0; nt < 16; ++nt)
#pragma unroll
        for (int r = 0; r < 4; ++r) acc[nt][r] *= scr[r];   // positive factor: ordering-safe

#pragma unroll
    for (int r = 0; r < 4; ++r) {
        // pass 1: max / argmax (first occurrence) / 2nd-max
        float m1 = -INFINITY, m2 = -INFINITY; int id = 0x7fffffff;
#pragma unroll
        for (int nt = 0; nt < 16; ++nt) {
            if (vbits & (1 << nt)) {
                const float d = acc[nt][r];
                if (d > m1)      { m2 = m1; m1 = d; id = nt * 16 + m; }
                else if (d > m2) { m2 = d; }
            }
        }
#pragma unroll
        for (int sh = 1; sh < 16; sh <<= 1) {   // reduce over m (protos), within quad
            const float om1 = __shfl_xor(m1, sh);
            const float om2 = __shfl_xor(m2, sh);
            const int   oid = __shfl_xor(id, sh);
            if (om1 > m1) { m2 = fmaxf(m1, om2); m1 = om1; id = oid; }
            else { if (om1 == m1 && oid < id) id = oid; m2 = fmaxf(m2, om1); }
        }
        const int posg = b * HW + pos0 + w * 16 + quad * 4 + r;
        if (m == 0) {
            out[OUT_ASSIGN + posg] = (float)id;
            if (m1 - m2 < GAP_THRESH) {          // near-tie -> exact fp64 recheck
                const int slot = atomicAdd(counter, 1);
                if (slot < MAXSUS) suspects[slot] = posg;
            }
        }
        // pass 2: softmax denominator and weighted sum (all lanes hold m1)
        float se = 0.f, sw = 0.f;
#pragma unroll
        for (int nt = 0; nt < 16; ++nt) {
            if (vbits & (1 << nt)) {
                const float d = acc[nt][r];
                const float e = __expf(d - m1);
                se += e; sw = fmaf(e, d, sw);
            }
        }
#pragma unroll
        for (int sh = 1; sh < 16; sh <<= 1) {
            se += __shfl_xor(se, sh);
            sw += __shfl_xor(sw, sh);
        }
        if (m == 0) out[posg] = sw / se;
    }
}

// ---------------------------------------------------------------------------
// Recheck: exact fp64 argmax for near-tie positions. Batches 16 suspects per
// block iteration: q columns staged to LDS in parallel, protos streamed once
// per batch. First-occurrence tie-break like jnp.argmax.
// ---------------------------------------------------------------------------
__global__ __launch_bounds__(256)
void recheck_kernel(const float* __restrict__ qry, const double* __restrict__ pn64,
                    const int* __restrict__ valid, const int* __restrict__ counter,
                    const int* __restrict__ suspects, float* __restrict__ out)
{
    __shared__ float  qsh[16][256];
    __shared__ double pd[4];
    __shared__ int    pi[4];
    const int t = threadIdx.x;
    const int w = t >> 6, l = t & 63;
    int n = *counter; if (n > MAXSUS) n = MAXSUS;
    const int nb = (n + 15) >> 4;

    for (int batch = blockIdx.x; batch < nb; batch += gridDim.x) {
        const int base = batch * 16;
        const int cnt = (n - base < 16) ? (n - base) : 16;
        for (int s = 0; s < cnt; ++s) {
            const int pos = suspects[base + s];
            qsh[s][t] = qry[(size_t)(pos >> 12) * (C * HW) + (size_t)t * HW + (pos & (HW - 1))];
        }
        __syncthreads();

        double acc[16];
#pragma unroll
        for (int s = 0; s < 16; ++s) acc[s] = 0.0;
        const double* pr = pn64 + (size_t)t * C;   // thread t = proto t
#pragma unroll 4
        for (int c = 0; c < C; ++c) {
            const double pv = pr[c];
#pragma unroll
            for (int s = 0; s < 16; ++s) acc[s] = fma((double)qsh[s][c], pv, acc[s]);
        }
        const bool vl = valid[t] != 0;
        for (int s = 0; s < cnt; ++s) {
            double dv = vl ? acc[s] : -INFINITY;
            int id = t;
#pragma unroll
            for (int sh = 1; sh < 64; sh <<= 1) {
                const double od = __shfl_xor(dv, sh);
                const int    oi = __shfl_xor(id, sh);
                if (od > dv || (od == dv && oi < id)) { dv = od; id = oi; }
            }
            if (l == 0) { pd[w] = dv; pi[w] = id; }
            __syncthreads();
            if (t == 0) {
                double bd = pd[0]; int bi = pi[0];
                for (int ww = 1; ww < 4; ++ww)
                    if (pd[ww] > bd || (pd[ww] == bd && pi[ww] < bi)) { bd = pd[ww]; bi = pi[ww]; }
                out[OUT_ASSIGN + suspects[base + s]] = (float)bi;
            }
            __syncthreads();
        }
    }
}

// ---------------------------------------------------------------------------
extern "C" void kernel_launch(void* const* d_in, const int* in_sizes, int n_in,
                              void* d_out, int out_size, void* d_ws, size_t ws_size,
                              hipStream_t stream)
{
    const float* qry   = (const float*)d_in[0];
    const float* sup_x = (const float*)d_in[1];
    const float* sup_y = (const float*)d_in[2];
    float* out = (float*)d_out;
    char*  ws  = (char*)d_ws;

    // ws layout (~1.03 MiB total)
    unsigned short* pB       = (unsigned short*)(ws);            // 256 KiB frag-order split-bf16 protos
    double*         pn64     = (double*)(ws + 256 * 1024);       // 512 KiB
    int*            valid    = (int*)(ws + 768 * 1024);          // 1 KiB
    int*            counter  = (int*)(ws + 768 * 1024 + 1024);   // 4 B
    int*            suspects = (int*)(ws + 768 * 1024 + 2048);   // 256 KiB

    prep_kernel<<<dim3(P), dim3(256), 0, stream>>>(sup_x, sup_y, out, pB, pn64, valid, counter);
    dist_kernel<<<dim3(BQ * (HW / 64)), dim3(256), 0, stream>>>(qry, pB, valid, out, counter, suspects);
    recheck_kernel<<<dim3(256), dim3(256), 0, stream>>>(qry, pn64, valid, counter, suspects, out);
}

// Round 2
// 292.195 us; speedup vs baseline: 1.1514x; 1.1514x over previous
//
#include <hip/hip_runtime.h>
#include <math.h>

// Problem constants
constexpr int BQ = 32;       // query batch
constexpr int C  = 256;      // channels
constexpr int HW = 4096;     // 64*64
constexpr int W  = 64;
constexpr int P  = 256;      // protos (4 * 8 * 8)
constexpr float THRESH = 0.95f;
constexpr float SCALE  = 20.0f;
constexpr float EPSF   = 1e-4f;
constexpr double EPSD  = 1e-4;
constexpr float GAP_THRESH = 2e-3f;   // split-bf16 dist err ~5e-4 -> 4x margin
constexpr int MAXSUS = 65536;

// d_out layout: pred [0, 131072) | debug_assign [131072, 262144) | proto_grid [262144, 278528)
constexpr int OUT_ASSIGN = BQ * HW;
constexpr int OUT_GRID   = 2 * BQ * HW;

typedef __attribute__((ext_vector_type(8))) short short8;
typedef __attribute__((ext_vector_type(4))) float floatx4;

static __device__ __forceinline__ unsigned short f2bf(float x) {
    unsigned u = __float_as_uint(x);
    u += 0x7FFFu + ((u >> 16) & 1u);     // round-to-nearest-even (no NaN inputs)
    return (unsigned short)(u >> 16);
}
static __device__ __forceinline__ float bf2f(unsigned short h) {
    return __uint_as_float(((unsigned)h) << 16);
}

// Fragment-order offset (ushort units): [tile][ks][h][lane][j], lane = quad*16 + idx,
// element j of lane <-> k = ks*32 + quad*8 + j. A and B use the IDENTICAL map, so
// any k-permutation cancels in the MFMA contraction.
#define FRAGOFF(tile, ks, h, lane) (((((tile) * 8 + (ks)) * 2 + (h)) * 64 + (lane)) * 8)

// async global->LDS, 16 B/lane; LDS dest = wave-uniform base + lane*16
static __device__ __forceinline__ void gl_lds16(const unsigned short* gp, unsigned short* lp) {
    __builtin_amdgcn_global_load_lds(
        (const __attribute__((address_space(1))) unsigned int*)gp,
        (__attribute__((address_space(3))) unsigned int*)lp, 16, 0, 0);
}

// ---------------------------------------------------------------------------
// Prep: pooled protos (fp64 normalize) -> split-bf16 frag-order pB + fp64 pn64,
// valid flags, proto_grid output, zero suspect counter. Block=proto, thread=channel.
// ---------------------------------------------------------------------------
__global__ __launch_bounds__(256)
void prep_kernel(const float* __restrict__ sup_x, const float* __restrict__ sup_y,
                 float* __restrict__ out, unsigned short* __restrict__ pB,
                 double* __restrict__ pn64, int* __restrict__ valid,
                 int* __restrict__ counter)
{
    const int p = blockIdx.x;     // proto index = s*64 + gy*8 + gx
    const int t = threadIdx.x;    // channel
    const int s = p >> 6, gy = (p >> 3) & 7, gx = p & 7;

    const float* base = sup_x + ((size_t)(s * C + t)) * HW + (gy * 8) * W + gx * 8;
    double sum = 0.0;
#pragma unroll
    for (int r = 0; r < 8; ++r) {
        const float4 a  = *(const float4*)(base + r * W);
        const float4 bq = *(const float4*)(base + r * W + 4);
        sum += (double)a.x;  sum += (double)a.y;  sum += (double)a.z;  sum += (double)a.w;
        sum += (double)bq.x; sum += (double)bq.y; sum += (double)bq.z; sum += (double)bq.w;
    }
    const double mean = sum * (1.0 / 64.0);

    __shared__ double red[256];
    red[t] = mean * mean;
    __syncthreads();
    for (int off = 128; off > 0; off >>= 1) {
        if (t < off) red[t] += red[t + off];
        __syncthreads();
    }
    const double nrm = sqrt(red[0]);
    const double pnv = mean / fmax(nrm, EPSD);
    pn64[(size_t)p * C + t] = pnv;

    // split-bf16 frag-order store: nt=p>>4, n-idx=p&15; ks=c>>5, quad=(c>>3)&3, j=c&7
    const float pnf = (float)pnv;
    const unsigned short phi = f2bf(pnf);
    const unsigned short plo = f2bf(pnf - bf2f(phi));
    const int nt = p >> 4, ks = t >> 5, lane = (((t >> 3) & 3) << 4) | (p & 15), j = t & 7;
    pB[FRAGOFF(nt, ks, 0, lane) + j] = phi;
    pB[FRAGOFF(nt, ks, 1, lane) + j] = plo;

    bool mybit = false;
    if (t < 64) {
        const int r = t >> 3, k = t & 7;
        mybit = sup_y[s * HW + (gy * 8 + r) * W + gx * 8 + k] > THRESH;
    }
    const unsigned long long bm = __ballot(mybit);   // wave 0 carries t=0..63
    if (t == 0) {
        valid[p] = (__popcll(bm) > 32) ? 1 : 0;      // mask_pooled > 0.5
        if (p == 0) *counter = 0;
    }
    if (t < 64) {
        const int i = p * 64 + t;
        out[OUT_GRID + i] = (sup_y[i] > THRESH) ? 1.0f : 0.0f;
    }
}

// ---------------------------------------------------------------------------
// Main: split-bf16 MFMA dists + fused softmax/argmax/pred.
// Block = 64 positions (4 waves); wave w owns pos-tile w (16 pos) x ALL 256 protos.
//
// R2 change: OCCUPANCY, not pipelining. R1's double-buffer proved the exposed
// vmcnt drain was NOT dominant (123->135 us). The limiter is 2 waves/SIMD
// (96 arch VGPR + 64 AGPR acc > 128 unified). Fix: per-ks A STREAMING -
// ah[ks]/al[ks] was only consumed in iteration ks, so keeping all 8 in regs
// (64 VGPRs) bought nothing. Now: 8-float prefetch buffer for A(ks+1) + 8-VGPR
// converted fragment for A(ks); convert VALU (~160cyc) fills the B-stage drain
// window. ssq accumulates across the loop; scale broadcast via 4 __shfl
// (scale_lds removed). Arch VGPRs ~96 -> ~60; launch_bounds(256,4) -> 128-reg
// unified budget -> 4 waves/SIMD, 4 blocks/CU (LDS 33.25 KB x 4 = 133 KB).
// Single-buffer 2-barrier loop (R0's proven structure); per-ks drains overlap
// across 4 independent blocks per CU.
// Spill signature if the ~60-arch estimate is wrong: WRITE_SIZE +tens of MB.
// ---------------------------------------------------------------------------
__global__ __launch_bounds__(256, 4)
void dist_kernel(const float* __restrict__ qry, const unsigned short* __restrict__ pB,
                 const int* __restrict__ valid, float* __restrict__ out,
                 int* __restrict__ counter, int* __restrict__ suspects)
{
    __shared__ unsigned short ldsB[16 * 2 * 64 * 8];   // 32 KiB: [nt][h][lane][j]
    __shared__ int validLds[P];                        // 1 KiB

    const int t    = threadIdx.x;
    const int w    = t >> 6;      // wave -> pos-tile
    const int l    = t & 63;
    const int quad = l >> 4;
    const int m    = l & 15;

    const int b    = blockIdx.x >> 6;
    const int pos0 = (blockIdx.x & 63) * 64;

    validLds[t] = valid[t];

    // lane l covers pos = pos0 + w*16 + m, k = ks*32 + quad*8 + j
    const float* qp = qry + (size_t)b * C * HW + pos0 + w * 16 + m;

    floatx4 acc[16];
#pragma unroll
    for (int nt = 0; nt < 16; ++nt) acc[nt] = (floatx4){0.f, 0.f, 0.f, 0.f};

    // prologue: issue A loads for ks=0 (drained by the first barrier)
    float vbuf[8];
#pragma unroll
    for (int j = 0; j < 8; ++j)
        vbuf[j] = qp[(size_t)(quad * 8 + j) * HW];

    float ssq = 0.f;
#pragma unroll
    for (int ks = 0; ks < 8; ++ks) {
        __syncthreads();                 // (a) prev chunk's LDS readers done; A(ks) drained
        // stage B(ks): 32 chunks of 1 KiB; wave w stages chunks w*8..w*8+7
#pragma unroll
        for (int i = 0; i < 8; ++i) {
            const int idx = w * 8 + i, nt = idx >> 1, h = idx & 1;
            gl_lds16(pB + FRAGOFF(nt, ks, h, 0) + l * 8,
                     &ldsB[(nt * 2 + h) * 512]);
        }
        // convert A(ks) from vbuf (VALU work overlaps the B-stage flight)
        short8 h8, l8;
#pragma unroll
        for (int j = 0; j < 8; ++j) {
            const float v = vbuf[j];
            ssq = fmaf(v, v, ssq);
            const unsigned short hi = f2bf(v);
            h8[j] = (short)hi;
            l8[j] = (short)f2bf(v - bf2f(hi));
        }
        // prefetch A(ks+1) (drained at barrier (b) below; ready next iteration)
        if (ks < 7) {
#pragma unroll
            for (int j = 0; j < 8; ++j)
                vbuf[j] = qp[(size_t)((ks + 1) * 32 + quad * 8 + j) * HW];
        }
        __syncthreads();                 // (b) vmcnt drained -> B(ks) visible
#pragma unroll
        for (int nt = 0; nt < 16; ++nt) {
            const short8 bh = *(const short8*)&ldsB[((nt * 2 + 0) * 64 + l) * 8];
            const short8 bl = *(const short8*)&ldsB[((nt * 2 + 1) * 64 + l) * 8];
            acc[nt] = __builtin_amdgcn_mfma_f32_16x16x32_bf16(h8, bh, acc[nt], 0, 0, 0);
            acc[nt] = __builtin_amdgcn_mfma_f32_16x16x32_bf16(h8, bl, acc[nt], 0, 0, 0);
            acc[nt] = __builtin_amdgcn_mfma_f32_16x16x32_bf16(l8, bh, acc[nt], 0, 0, 0);
        }
    }

    // ||q||^2 for pos w*16+m: sum the 4 quads (lanes differing in bits 4,5)
    ssq += __shfl_xor(ssq, 16);
    ssq += __shfl_xor(ssq, 32);
    const float scalev = SCALE / fmaxf(sqrtf(ssq), EPSF);

    // ---- epilogue (wave-local). C/D: proto = nt*16 + m, pos-in-tile = quad*4 + r ----
    int vbits = 0;
#pragma unroll
    for (int nt = 0; nt < 16; ++nt) vbits |= validLds[nt * 16 + m] << nt;

    float scr[4];
#pragma unroll
    for (int r = 0; r < 4; ++r) scr[r] = __shfl(scalev, quad * 4 + r);   // lane quad*4+r holds pos w*16+quad*4+r
#pragma unroll
    for (int nt = 0; nt < 16; ++nt)
#pragma unroll
        for (int r = 0; r < 4; ++r) acc[nt][r] *= scr[r];   // positive factor: ordering-safe

#pragma unroll
    for (int r = 0; r < 4; ++r) {
        // pass 1: max / argmax (first occurrence) / 2nd-max
        float m1 = -INFINITY, m2 = -INFINITY; int id = 0x7fffffff;
#pragma unroll
        for (int nt = 0; nt < 16; ++nt) {
            if (vbits & (1 << nt)) {
                const float d = acc[nt][r];
                if (d > m1)      { m2 = m1; m1 = d; id = nt * 16 + m; }
                else if (d > m2) { m2 = d; }
            }
        }
#pragma unroll
        for (int sh = 1; sh < 16; sh <<= 1) {   // reduce over m (protos), within quad
            const float om1 = __shfl_xor(m1, sh);
            const float om2 = __shfl_xor(m2, sh);
            const int   oid = __shfl_xor(id, sh);
            if (om1 > m1) { m2 = fmaxf(m1, om2); m1 = om1; id = oid; }
            else { if (om1 == m1 && oid < id) id = oid; m2 = fmaxf(m2, om1); }
        }
        const int posg = b * HW + pos0 + w * 16 + quad * 4 + r;
        if (m == 0) {
            out[OUT_ASSIGN + posg] = (float)id;
            if (m1 - m2 < GAP_THRESH) {          // near-tie -> exact fp64 recheck
                const int slot = atomicAdd(counter, 1);
                if (slot < MAXSUS) suspects[slot] = posg;
            }
        }
        // pass 2: softmax denominator and weighted sum (all lanes hold m1)
        float se = 0.f, sw = 0.f;
#pragma unroll
        for (int nt = 0; nt < 16; ++nt) {
            if (vbits & (1 << nt)) {
                const float d = acc[nt][r];
                const float e = __expf(d - m1);
                se += e; sw = fmaf(e, d, sw);
            }
        }
#pragma unroll
        for (int sh = 1; sh < 16; sh <<= 1) {
            se += __shfl_xor(se, sh);
            sw += __shfl_xor(sw, sh);
        }
        if (m == 0) out[posg] = sw / se;
    }
}

// ---------------------------------------------------------------------------
// Recheck: exact fp64 argmax for near-tie positions. Batches 16 suspects per
// block iteration: q columns staged to LDS in parallel, protos streamed once
// per batch. First-occurrence tie-break like jnp.argmax.
// ---------------------------------------------------------------------------
__global__ __launch_bounds__(256)
void recheck_kernel(const float* __restrict__ qry, const double* __restrict__ pn64,
                    const int* __restrict__ valid, const int* __restrict__ counter,
                    const int* __restrict__ suspects, float* __restrict__ out)
{
    __shared__ float  qsh[16][256];
    __shared__ double pd[4];
    __shared__ int    pi[4];
    const int t = threadIdx.x;
    const int w = t >> 6, l = t & 63;
    int n = *counter; if (n > MAXSUS) n = MAXSUS;
    const int nb = (n + 15) >> 4;

    for (int batch = blockIdx.x; batch < nb; batch += gridDim.x) {
        const int base = batch * 16;
        const int cnt = (n - base < 16) ? (n - base) : 16;
        for (int s = 0; s < cnt; ++s) {
            const int pos = suspects[base + s];
            qsh[s][t] = qry[(size_t)(pos >> 12) * (C * HW) + (size_t)t * HW + (pos & (HW - 1))];
        }
        __syncthreads();

        double acc[16];
#pragma unroll
        for (int s = 0; s < 16; ++s) acc[s] = 0.0;
        const double* pr = pn64 + (size_t)t * C;   // thread t = proto t
#pragma unroll 4
        for (int c = 0; c < C; ++c) {
            const double pv = pr[c];
#pragma unroll
            for (int s = 0; s < 16; ++s) acc[s] = fma((double)qsh[s][c], pv, acc[s]);
        }
        const bool vl = valid[t] != 0;
        for (int s = 0; s < cnt; ++s) {
            double dv = vl ? acc[s] : -INFINITY;
            int id = t;
#pragma unroll
            for (int sh = 1; sh < 64; sh <<= 1) {
                const double od = __shfl_xor(dv, sh);
                const int    oi = __shfl_xor(id, sh);
                if (od > dv || (od == dv && oi < id)) { dv = od; id = oi; }
            }
            if (l == 0) { pd[w] = dv; pi[w] = id; }
            __syncthreads();
            if (t == 0) {
                double bd = pd[0]; int bi = pi[0];
                for (int ww = 1; ww < 4; ++ww)
                    if (pd[ww] > bd || (pd[ww] == bd && pi[ww] < bi)) { bd = pd[ww]; bi = pi[ww]; }
                out[OUT_ASSIGN + suspects[base + s]] = (float)bi;
            }
            __syncthreads();
        }
    }
}

// ---------------------------------------------------------------------------
extern "C" void kernel_launch(void* const* d_in, const int* in_sizes, int n_in,
                              void* d_out, int out_size, void* d_ws, size_t ws_size,
                              hipStream_t stream)
{
    const float* qry   = (const float*)d_in[0];
    const float* sup_x = (const float*)d_in[1];
    const float* sup_y = (const float*)d_in[2];
    float* out = (float*)d_out;
    char*  ws  = (char*)d_ws;

    // ws layout (~1.03 MiB total)
    unsigned short* pB       = (unsigned short*)(ws);            // 256 KiB frag-order split-bf16 protos
    double*         pn64     = (double*)(ws + 256 * 1024);       // 512 KiB
    int*            valid    = (int*)(ws + 768 * 1024);          // 1 KiB
    int*            counter  = (int*)(ws + 768 * 1024 + 1024);   // 4 B
    int*            suspects = (int*)(ws + 768 * 1024 + 2048);   // 256 KiB

    prep_kernel<<<dim3(P), dim3(256), 0, stream>>>(sup_x, sup_y, out, pB, pn64, valid, counter);
    dist_kernel<<<dim3(BQ * (HW / 64)), dim3(256), 0, stream>>>(qry, pB, valid, out, counter, suspects);
    recheck_kernel<<<dim3(256), dim3(256), 0, stream>>>(qry, pn64, valid, counter, suspects, out);
}